// Round 6
// baseline (145.768 us; speedup 1.0000x reference)
//
#include <hip/hip_runtime.h>

#define D_DIM 4096
#define N_TOK 4096
#define K_EXP 64
#define R_RANK 16
#define KR 1024               // K_EXP * R_RANK
#define SCALE_F 2.0f          // ALPHA / RANK
#define SPLIT_S 32
#define KC_S (D_DIM / SPLIT_S)   // 128
#define SPLIT_G 4
#define KC_G (D_DIM / SPLIT_G)   // 1024

typedef __attribute__((ext_vector_type(8))) short short8_t;   // 8 x bf16
typedef __attribute__((ext_vector_type(4))) float f32x4_t;
typedef __attribute__((ext_vector_type(4))) unsigned short u16x4_t;

__device__ __forceinline__ unsigned short f2bf(float f) {
  unsigned int u = __builtin_bit_cast(unsigned int, f);
  u += 0x7fffu + ((u >> 16) & 1u);          // RTNE
  return (unsigned short)(u >> 16);
}
__device__ __forceinline__ float bf2f(unsigned short h) {
  return __builtin_bit_cast(float, ((unsigned int)h) << 16);
}

// async global->LDS, 16B per lane. LDS dest must be wave-uniform base + lane*16.
__device__ __forceinline__ void gload16(const void* g, void* l) {
  __builtin_amdgcn_global_load_lds(
      (const __attribute__((address_space(1))) unsigned int*)g,
      (__attribute__((address_space(3))) unsigned int*)l, 16, 0, 0);
}

#define BARR() __builtin_amdgcn_s_barrier()
#define FENCE() __builtin_amdgcn_sched_barrier(0)
#define WAIT_LGKM0() asm volatile("s_waitcnt lgkmcnt(0)" ::: "memory")
#define WAIT_VM(n) asm volatile("s_waitcnt vmcnt(" #n ")" ::: "memory")

// ---------------- pack kernels ----------------
__global__ void pack_f32_to_bf16(const float* __restrict__ in,
                                 unsigned short* __restrict__ out, int n4) {
  int stride = gridDim.x * blockDim.x;
  for (int i = blockIdx.x * blockDim.x + threadIdx.x; i < n4; i += stride) {
    f32x4_t v = *(const f32x4_t*)(in + (size_t)i * 4);
    u16x4_t o;
    o[0] = f2bf(v[0]); o[1] = f2bf(v[1]); o[2] = f2bf(v[2]); o[3] = f2bf(v[3]);
    *(u16x4_t*)(out + (size_t)i * 4) = o;
  }
}

// B (K,D,R) f32 -> Wb (D, K*R) bf16 : Wb[d][k*16+r] = B[k][d][r]
__global__ void pack_b_kernel(const float* __restrict__ B,
                              unsigned short* __restrict__ Wb, int n) {
  int stride = gridDim.x * blockDim.x;
  for (int i = blockIdx.x * blockDim.x + threadIdx.x; i < n; i += stride) {
    int k   = i >> 14;
    int rem = i & 16383;
    int d   = rem >> 2;
    int r4  = (rem & 3) * 4;
    f32x4_t v = *(const f32x4_t*)(B + ((size_t)(k * D_DIM + d) * R_RANK + r4));
    u16x4_t o;
    o[0] = f2bf(v[0]); o[1] = f2bf(v[1]); o[2] = f2bf(v[2]); o[3] = f2bf(v[3]);
    *(u16x4_t*)(Wb + ((size_t)d * KR + k * R_RANK + r4)) = o;
  }
}

// ---------------- router scores via MFMA (hi/lo bf16 split, split-K=32) ----------------
// Register-prefetched global loads; also emits Xb (bf16 hi) for GEMM1.
__global__ __launch_bounds__(256)
void scores_mfma(const float* __restrict__ x, const float* __restrict__ Wr,
                 float* __restrict__ P, unsigned short* __restrict__ Xb) {
  __shared__ unsigned short Ah[128 * 32];
  __shared__ unsigned short Al[128 * 32];
  __shared__ unsigned short Bh[64 * 32];
  __shared__ unsigned short Bl[64 * 32];
  int t = threadIdx.x;
  int brow = blockIdx.x * 128;
  int kcb = blockIdx.y * KC_S;
  int wid = t >> 6, lane = t & 63;
  int wr = wid >> 1, wc = wid & 1;
  int lr = lane & 15, kh = lane >> 4;

  const int arow = t >> 3, ac4 = (t & 7) * 4;     // x: 4 rows per thread-slot step
  const int wrow = t >> 3, wc4 = (t & 7) * 4;

  f32x4_t acc[4][2] = {};
  f32x4_t av[4], wv[2], avn[4], wvn[2];

  // preload step 0
#pragma unroll
  for (int i = 0; i < 4; ++i)
    av[i] = *(const f32x4_t*)(x + (size_t)(brow + arow + i * 32) * D_DIM + kcb + ac4);
#pragma unroll
  for (int i = 0; i < 2; ++i)
    wv[i] = *(const f32x4_t*)(Wr + (size_t)(wrow + i * 32) * D_DIM + kcb + wc4);

  for (int k0 = kcb; k0 < kcb + KC_S; k0 += 32) {
    if (k0 + 32 < kcb + KC_S) {                   // issue next-step loads early
#pragma unroll
      for (int i = 0; i < 4; ++i)
        avn[i] = *(const f32x4_t*)(x + (size_t)(brow + arow + i * 32) * D_DIM + k0 + 32 + ac4);
#pragma unroll
      for (int i = 0; i < 2; ++i)
        wvn[i] = *(const f32x4_t*)(Wr + (size_t)(wrow + i * 32) * D_DIM + k0 + 32 + wc4);
    }
    __syncthreads();                              // prev step's frag reads done
#pragma unroll
    for (int i = 0; i < 4; ++i) {
      int row = arow + i * 32;
      u16x4_t h, l;
#pragma unroll
      for (int j = 0; j < 4; ++j) { h[j] = f2bf(av[i][j]); l[j] = f2bf(av[i][j] - bf2f(h[j])); }
      *(u16x4_t*)(Ah + row * 32 + ac4) = h;
      *(u16x4_t*)(Al + row * 32 + ac4) = l;
      *(u16x4_t*)(Xb + (size_t)(brow + row) * D_DIM + k0 + ac4) = h;   // fused pack
    }
#pragma unroll
    for (int i = 0; i < 2; ++i) {
      int row = wrow + i * 32;
      u16x4_t h, l;
#pragma unroll
      for (int j = 0; j < 4; ++j) { h[j] = f2bf(wv[i][j]); l[j] = f2bf(wv[i][j] - bf2f(h[j])); }
      *(u16x4_t*)(Bh + row * 32 + wc4) = h;
      *(u16x4_t*)(Bl + row * 32 + wc4) = l;
    }
    __syncthreads();
    short8_t ah[4], al[4], bh[2], bl[2];
#pragma unroll
    for (int m = 0; m < 4; ++m) {
      ah[m] = *(const short8_t*)(Ah + (wr * 64 + m * 16 + lr) * 32 + kh * 8);
      al[m] = *(const short8_t*)(Al + (wr * 64 + m * 16 + lr) * 32 + kh * 8);
    }
#pragma unroll
    for (int n = 0; n < 2; ++n) {
      bh[n] = *(const short8_t*)(Bh + (wc * 32 + n * 16 + lr) * 32 + kh * 8);
      bl[n] = *(const short8_t*)(Bl + (wc * 32 + n * 16 + lr) * 32 + kh * 8);
    }
#pragma unroll
    for (int m = 0; m < 4; ++m)
#pragma unroll
      for (int n = 0; n < 2; ++n) {
        acc[m][n] = __builtin_amdgcn_mfma_f32_16x16x32_bf16(ah[m], bh[n], acc[m][n], 0, 0, 0);
        acc[m][n] = __builtin_amdgcn_mfma_f32_16x16x32_bf16(al[m], bh[n], acc[m][n], 0, 0, 0);
        acc[m][n] = __builtin_amdgcn_mfma_f32_16x16x32_bf16(ah[m], bl[n], acc[m][n], 0, 0, 0);
      }
#pragma unroll
    for (int i = 0; i < 4; ++i) av[i] = avn[i];
#pragma unroll
    for (int i = 0; i < 2; ++i) wv[i] = wvn[i];
  }

  float* Pb = P + (size_t)blockIdx.y * N_TOK * K_EXP;
#pragma unroll
  for (int m = 0; m < 4; ++m)
#pragma unroll
    for (int n = 0; n < 2; ++n)
#pragma unroll
      for (int j = 0; j < 4; ++j) {
        int row = brow + wr * 64 + m * 16 + kh * 4 + j;
        int e = wc * 32 + n * 16 + lr;
        Pb[(size_t)row * K_EXP + e] = acc[m][n][j];
      }
}

// ---------------- per-token top-16 + softmax -> dense G (N,64) ----------------
__global__ void topk_kernel(const float* __restrict__ P, float* __restrict__ G) {
  int wid = threadIdx.x >> 6, lane = threadIdx.x & 63;
  int n = blockIdx.x * 4 + wid;
  float rem = 0.f;
#pragma unroll
  for (int c = 0; c < SPLIT_S; ++c)
    rem += P[((size_t)c * N_TOK + n) * K_EXP + lane];
  float topv[16]; int topi[16];
#pragma unroll
  for (int it = 0; it < 16; ++it) {
    float bv = rem; int bi = lane;
#pragma unroll
    for (int off = 32; off >= 1; off >>= 1) {
      float ov = __shfl_xor(bv, off);
      int oi = __shfl_xor(bi, off);
      if (ov > bv || (ov == bv && oi < bi)) { bv = ov; bi = oi; }
    }
    topv[it] = bv; topi[it] = bi;
    if (lane == bi) rem = -1e30f;
  }
  float mx = topv[0];
  float s = 0.f;
#pragma unroll
  for (int j = 0; j < 16; ++j) s += expf(topv[j] - mx);
  float g = 0.f;
#pragma unroll
  for (int j = 0; j < 16; ++j)
    if (topi[j] == lane) g = expf(topv[j] - mx) / s;
  G[(size_t)n * K_EXP + lane] = g;
}

// ---------------- 8-phase 256x256 MFMA GEMM (C = A(M,KD-slice) * B(N,KD-slice)^T) ----
// 512 thr = 8 waves (2M x 4N), BK=64, 16 K-tiles/block, 2 LDS buffers (128 KiB).
// T2 swizzle: linear gload_lds dest + inverse-permuted global src + XOR'd ds_read.
// Stage schedule (group t: phases p0..p3 compute tile t from buf[t&1]):
//   p0: stage A1,A3(t+1); p1: stage B0,B1(t+2), vmcnt(10);
//   p2: stage B2,B3(t+2); p3: stage A0,A2(t+2), vmcnt(8).
// ONE sched_barrier per phase (rule 18, after lgkmcnt(0)) — no other order pinning.
template <int KD, int EPI>   // EPI 0: bf16 partial out (stride KR); 1: f32*SCALE (stride D_DIM)
__global__ __launch_bounds__(512, 2)
void gemm8ph(const unsigned short* __restrict__ Aop,
             const unsigned short* __restrict__ Bop,
             void* __restrict__ Cout) {
  extern __shared__ unsigned short lds[];   // 2 x (A 256x64 + B 256x64) = 65536 shorts
  const int t = threadIdx.x;
  const int wid = t >> 6, lane = t & 63;
  const int wm = wid >> 2, wn = wid & 3;
  const int lr = lane & 15, kh = lane >> 4;

  int brow, bcol, kbeg;
  unsigned short* outb = nullptr;
  float* outf = nullptr;
  {
    int b = blockIdx.x;                    // 256 blocks, XCD-bijective remap
    int logical = (b & 7) * 32 + (b >> 3);
    if constexpr (EPI == 0) {
      int zb = logical >> 6;               // K split (4)
      int rem = logical & 63;
      brow = (rem >> 2) * 256;
      bcol = (rem & 3) * 256;
      kbeg = zb * KC_G;
      outb = (unsigned short*)Cout + (size_t)zb * N_TOK * KR;
    } else {
      brow = (logical >> 4) * 256;
      bcol = (logical & 15) * 256;
      kbeg = 0;
      outf = (float*)Cout;
    }
  }

  // staging: thread tau covers unit-linear LDS [tau*8, tau*8+8) shorts;
  // source col chunk permuted by (row&7) so swizzled READ sees logical layout.
  const int srow = t >> 3;                               // 0..63 within unit
  const int scoff = (((t & 7) ^ (srow & 7)) * 8);        // shorts
  const int ldoff = t * 8;                               // shorts
  const unsigned short* Abase = Aop + (size_t)(brow + srow) * KD + kbeg + scoff;
  const unsigned short* Bbase = Bop + (size_t)(bcol + srow) * KD + kbeg + scoff;

  auto stA = [&](int j, int T) {
    gload16(Abase + (size_t)j * 64 * KD + T * 64,
            lds + (T & 1) * 32768 + j * 4096 + ldoff);
  };
  auto stB = [&](int j, int T) {
    gload16(Bbase + (size_t)j * 64 * KD + T * 64,
            lds + (T & 1) * 32768 + 16384 + j * 4096 + ldoff);
  };
  // fragment reads (XOR-swizzled)
  auto rdA = [&](const unsigned short* LA, int m, int ks) -> short8_t {
    int r = wm * 128 + m * 16 + lr;
    int x = (ks * 32 + kh * 8) ^ ((lr & 7) << 3);
    return *(const short8_t*)(LA + r * 64 + x);
  };
  auto rdB = [&](const unsigned short* LB, int n, int ks) -> short8_t {
    int r = wn * 64 + n * 16 + lr;
    int x = (ks * 32 + kh * 8) ^ ((lr & 7) << 3);
    return *(const short8_t*)(LB + r * 64 + x);
  };

  f32x4_t acc[8][4] = {};
  short8_t bq[4][2], aq[2][2];

#define MFMA_QUAD(mb)                                                        \
  _Pragma("unroll")                                                          \
  for (int mm = 0; mm < 2; ++mm)                                             \
    _Pragma("unroll")                                                        \
    for (int n = 0; n < 4; ++n)                                              \
      _Pragma("unroll")                                                      \
      for (int ks = 0; ks < 2; ++ks)                                         \
        acc[(mb) + mm][n] = __builtin_amdgcn_mfma_f32_16x16x32_bf16(         \
            aq[mm][ks], bq[n][ks], acc[(mb) + mm][n], 0, 0, 0);

  // ---- prologue: tile0 full (8 units), tile1 B*,A0,A2 (6 units) = 14 loads
  stB(0, 0); stB(1, 0); stB(2, 0); stB(3, 0);
  stA(0, 0); stA(1, 0); stA(2, 0); stA(3, 0);
  stB(0, 1); stB(1, 1); stB(2, 1); stB(3, 1);
  stA(0, 1); stA(2, 1);
  WAIT_VM(6);                      // oldest 8 (tile 0) landed
  BARR();

  for (int tt = 0; tt < 16; ++tt) {
    const unsigned short* LA = lds + (tt & 1) * 32768;
    const unsigned short* LB = LA + 16384;
    // ---------- phase 0: all B frags + A m0,1 ----------
#pragma unroll
    for (int n = 0; n < 4; ++n) { bq[n][0] = rdB(LB, n, 0); bq[n][1] = rdB(LB, n, 1); }
    aq[0][0] = rdA(LA, 0, 0); aq[0][1] = rdA(LA, 0, 1);
    aq[1][0] = rdA(LA, 1, 0); aq[1][1] = rdA(LA, 1, 1);
    if (tt + 1 < 16) { stA(1, tt + 1); stA(3, tt + 1); }
    BARR(); WAIT_LGKM0(); FENCE();
    __builtin_amdgcn_s_setprio(1);
    MFMA_QUAD(0)
    __builtin_amdgcn_s_setprio(0);
    BARR();
    // ---------- phase 1: A m2,3 ----------
    aq[0][0] = rdA(LA, 2, 0); aq[0][1] = rdA(LA, 2, 1);
    aq[1][0] = rdA(LA, 3, 0); aq[1][1] = rdA(LA, 3, 1);
    if (tt + 2 < 16) { stB(0, tt + 2); stB(1, tt + 2); }
    WAIT_VM(10);
    BARR(); WAIT_LGKM0(); FENCE();
    __builtin_amdgcn_s_setprio(1);
    MFMA_QUAD(2)
    __builtin_amdgcn_s_setprio(0);
    BARR();
    // ---------- phase 2: A m4,5 ----------
    aq[0][0] = rdA(LA, 4, 0); aq[0][1] = rdA(LA, 4, 1);
    aq[1][0] = rdA(LA, 5, 0); aq[1][1] = rdA(LA, 5, 1);
    if (tt + 2 < 16) { stB(2, tt + 2); stB(3, tt + 2); }
    BARR(); WAIT_LGKM0(); FENCE();
    __builtin_amdgcn_s_setprio(1);
    MFMA_QUAD(4)
    __builtin_amdgcn_s_setprio(0);
    BARR();
    // ---------- phase 3: A m6,7 ----------
    aq[0][0] = rdA(LA, 6, 0); aq[0][1] = rdA(LA, 6, 1);
    aq[1][0] = rdA(LA, 7, 0); aq[1][1] = rdA(LA, 7, 1);
    if (tt + 2 < 16) { stA(0, tt + 2); stA(2, tt + 2); }
    WAIT_VM(8);
    BARR(); WAIT_LGKM0(); FENCE();
    __builtin_amdgcn_s_setprio(1);
    MFMA_QUAD(6)
    __builtin_amdgcn_s_setprio(0);
    BARR();
  }
#undef MFMA_QUAD

  // ---- epilogue ----
#pragma unroll
  for (int m = 0; m < 8; ++m) {
    int gr0 = brow + wm * 128 + m * 16 + kh * 4;
#pragma unroll
    for (int n = 0; n < 4; ++n) {
      int gc = bcol + wn * 64 + n * 16 + lr;
#pragma unroll
      for (int j = 0; j < 4; ++j) {
        if constexpr (EPI == 0)
          outb[(size_t)(gr0 + j) * KR + gc] = f2bf(acc[m][n][j]);
        else
          outf[(size_t)(gr0 + j) * D_DIM + gc] = acc[m][n][j] * SCALE_F;
      }
    }
  }
}

// ---------------- reduce split-K bf16 partials, apply gate, pack bf16 ----------------
__global__ void reduce_gate_pack(const unsigned short* __restrict__ Pgb,
                                 const float* __restrict__ G,
                                 unsigned short* __restrict__ Hgb) {
  int idx4 = blockIdx.x * blockDim.x + threadIdx.x;
  size_t i = (size_t)idx4 * 4;
  int n = (int)(i >> 10);
  int kr = (int)(i & 1023);
  float g = G[(size_t)n * K_EXP + (kr >> 4)];
  float s[4] = {0.f, 0.f, 0.f, 0.f};
#pragma unroll
  for (int z = 0; z < SPLIT_G; ++z) {
    u16x4_t v = *(const u16x4_t*)(Pgb + (size_t)z * N_TOK * KR + i);
#pragma unroll
    for (int j = 0; j < 4; ++j) s[j] += bf2f(v[j]);
  }
  u16x4_t o;
#pragma unroll
  for (int j = 0; j < 4; ++j) o[j] = f2bf(s[j] * g);
  *(u16x4_t*)(Hgb + i) = o;
}

// ---------------- launch ----------------
extern "C" void kernel_launch(void* const* d_in, const int* in_sizes, int n_in,
                              void* d_out, int out_size, void* d_ws, size_t ws_size,
                              hipStream_t stream) {
  const float* x  = (const float*)d_in[0];   // (2,2048,4096)
  const float* A  = (const float*)d_in[1];   // (64,16,4096)
  const float* B  = (const float*)d_in[2];   // (64,4096,16)
  const float* Wr = (const float*)d_in[3];   // (64,4096)
  float* out = (float*)d_out;

  char* ws = (char*)d_ws;
  size_t off = 0;
  auto alloc = [&](size_t bytes) { void* p = ws + off; off += (bytes + 255) & ~255ull; return p; };
  float*          P   = (float*)alloc((size_t)SPLIT_S * N_TOK * K_EXP * 4);   // 32 MB
  float*          G   = (float*)alloc((size_t)N_TOK * K_EXP * 4);             // 1 MB
  unsigned short* Xb  = (unsigned short*)alloc((size_t)N_TOK * D_DIM * 2);    // 32 MB
  unsigned short* Ab  = (unsigned short*)alloc((size_t)KR * D_DIM * 2);       // 8 MB
  unsigned short* Wb  = (unsigned short*)alloc((size_t)D_DIM * KR * 2);       // 8 MB
  unsigned short* Hgb = (unsigned short*)alloc((size_t)N_TOK * KR * 2);       // 8 MB
  unsigned short* Pgb = (unsigned short*)alloc((size_t)SPLIT_G * N_TOK * KR * 2); // 32 MB
  (void)ws_size; (void)in_sizes; (void)n_in; (void)out_size;

  // allow 128 KiB dynamic LDS (host-side attribute, idempotent, not a stream op)
  (void)hipFuncSetAttribute((const void*)&gemm8ph<D_DIM, 0>,
                            hipFuncAttributeMaxDynamicSharedMemorySize, 131072);
  (void)hipFuncSetAttribute((const void*)&gemm8ph<KR, 1>,
                            hipFuncAttributeMaxDynamicSharedMemorySize, 131072);

  pack_f32_to_bf16<<<1024, 256, 0, stream>>>(A, Ab, KR * D_DIM / 4);
  pack_b_kernel<<<1024, 256, 0, stream>>>(B, Wb, K_EXP * D_DIM * 4);

  scores_mfma<<<dim3(N_TOK / 128, SPLIT_S), 256, 0, stream>>>(x, Wr, P, Xb);
  topk_kernel<<<N_TOK / 4, 256, 0, stream>>>(P, G);

  // GEMM1: Pgb[z] = bf16(Xb @ Ab^T) over K-chunk z  (256 blocks: 16M x 4N x 4z)
  gemm8ph<D_DIM, 0><<<256, 512, 131072, stream>>>(Xb, Ab, Pgb);
  reduce_gate_pack<<<N_TOK * KR / 4 / 256, 256, 0, stream>>>(Pgb, G, Hgb);

  // GEMM2: out = SCALE * Hgb @ Wb^T  (256 blocks: 16M x 16N)
  gemm8ph<KR, 1><<<256, 512, 131072, stream>>>(Hgb, Wb, out);
}

// Round 7
// 136.310 us; speedup vs baseline: 1.0694x; 1.0694x over previous
//
#include <hip/hip_runtime.h>
#include <hip/hip_bf16.h>

#define D_DIM 4096
#define N_TOK 4096
#define K_EXP 64
#define R_RANK 16
#define KR 1024               // K_EXP * R_RANK
#define SCALE_F 2.0f          // ALPHA / RANK
#define SPLIT_S 16
#define KC_S (D_DIM / SPLIT_S)   // 256
#define SPLIT_G 4
#define KC_G (D_DIM / SPLIT_G)   // 1024

typedef __attribute__((ext_vector_type(8))) short short8_t;   // 8 x bf16
typedef __attribute__((ext_vector_type(4))) float f32x4_t;
typedef __attribute__((ext_vector_type(4))) unsigned short u16x4_t;

__device__ __forceinline__ unsigned short f2bf(float f) {
  unsigned int u = __builtin_bit_cast(unsigned int, f);
  u += 0x7fffu + ((u >> 16) & 1u);          // RTNE
  return (unsigned short)(u >> 16);
}
__device__ __forceinline__ float bf2f(unsigned short h) {
  return __builtin_bit_cast(float, ((unsigned int)h) << 16);
}

// hi/lo split of 8 f32 -> bf16 hi + bf16 lo (compiler-friendly casts)
__device__ __forceinline__ void cvt_hilo8(const f32x4_t a, const f32x4_t b,
                                          short8_t& h, short8_t& l) {
#pragma unroll
  for (int j = 0; j < 8; ++j) {
    float f = (j < 4) ? a[j & 3] : b[j & 3];
    __hip_bfloat16 hb = __float2bfloat16(f);
    float hf = __bfloat162float(hb);
    __hip_bfloat16 lb = __float2bfloat16(f - hf);
    h[j] = (short)__builtin_bit_cast(unsigned short, hb);
    l[j] = (short)__builtin_bit_cast(unsigned short, lb);
  }
}

// async global->LDS, 16B per lane. LDS dest must be wave-uniform base + lane*16.
__device__ __forceinline__ void gload16(const void* g, void* l) {
  __builtin_amdgcn_global_load_lds(
      (const __attribute__((address_space(1))) unsigned int*)g,
      (__attribute__((address_space(3))) unsigned int*)l, 16, 0, 0);
}

#define BARR() __builtin_amdgcn_s_barrier()
#define FENCE() __builtin_amdgcn_sched_barrier(0)
#define WAIT_LGKM0() asm volatile("s_waitcnt lgkmcnt(0)" ::: "memory")
#define WAIT_VM(n) asm volatile("s_waitcnt vmcnt(" #n ")" ::: "memory")

// ---------------- pack kernels ----------------
__global__ void pack_f32_to_bf16(const float* __restrict__ in,
                                 unsigned short* __restrict__ out, int n4) {
  int stride = gridDim.x * blockDim.x;
  for (int i = blockIdx.x * blockDim.x + threadIdx.x; i < n4; i += stride) {
    f32x4_t v = *(const f32x4_t*)(in + (size_t)i * 4);
    u16x4_t o;
    o[0] = f2bf(v[0]); o[1] = f2bf(v[1]); o[2] = f2bf(v[2]); o[3] = f2bf(v[3]);
    *(u16x4_t*)(out + (size_t)i * 4) = o;
  }
}

// B (K,D,R) f32 -> Wb (D, K*R) bf16 : Wb[d][k*16+r] = B[k][d][r]
__global__ void pack_b_kernel(const float* __restrict__ B,
                              unsigned short* __restrict__ Wb, int n) {
  int stride = gridDim.x * blockDim.x;
  for (int i = blockIdx.x * blockDim.x + threadIdx.x; i < n; i += stride) {
    int k   = i >> 14;
    int rem = i & 16383;
    int d   = rem >> 2;
    int r4  = (rem & 3) * 4;
    f32x4_t v = *(const f32x4_t*)(B + ((size_t)(k * D_DIM + d) * R_RANK + r4));
    u16x4_t o;
    o[0] = f2bf(v[0]); o[1] = f2bf(v[1]); o[2] = f2bf(v[2]); o[3] = f2bf(v[3]);
    *(u16x4_t*)(Wb + ((size_t)d * KR + k * R_RANK + r4)) = o;
  }
}

// Wr (64,4096) f32 -> Wrh, Wrl bf16 (hi/lo split)
__global__ void pack_wr(const float* __restrict__ Wr,
                        unsigned short* __restrict__ Wrh,
                        unsigned short* __restrict__ Wrl) {
  int i = blockIdx.x * blockDim.x + threadIdx.x;   // 65536 quads
  f32x4_t v = *(const f32x4_t*)(Wr + (size_t)i * 4);
  u16x4_t h, l;
#pragma unroll
  for (int j = 0; j < 4; ++j) {
    __hip_bfloat16 hb = __float2bfloat16(v[j]);
    float hf = __bfloat162float(hb);
    __hip_bfloat16 lb = __float2bfloat16(v[j] - hf);
    h[j] = __builtin_bit_cast(unsigned short, hb);
    l[j] = __builtin_bit_cast(unsigned short, lb);
  }
  *(u16x4_t*)(Wrh + (size_t)i * 4) = h;
  *(u16x4_t*)(Wrl + (size_t)i * 4) = l;
}

// ---------------- router scores v3: BK=64, reg-staged x, preconverted Wr ----------------
// grid (32, SPLIT_S). Emits P partials + fused Xb (bf16 hi of x).
__global__ __launch_bounds__(256)
void scores_mfma(const float* __restrict__ x,
                 const unsigned short* __restrict__ Wrh,
                 const unsigned short* __restrict__ Wrl,
                 float* __restrict__ P, unsigned short* __restrict__ Xb) {
  __shared__ unsigned short Ah[128 * 64];    // 16 KB, XOR-swizzled
  __shared__ unsigned short Al[128 * 64];    // 16 KB
  __shared__ unsigned short Wh[2][64 * 64];  // 2 x 8 KB (dbuf)
  __shared__ unsigned short Wl[2][64 * 64];  // 2 x 8 KB
  const int t = threadIdx.x;
  const int brow = blockIdx.x * 128;
  const int kcb = blockIdx.y * KC_S;
  const int wid = t >> 6, lane = t & 63;
  const int wr = wid >> 1, wc = wid & 1;
  const int lr = lane & 15, kh = lane >> 4;
  const int crow = t >> 3;          // 0..31 (row base; unit i adds i*32)
  const int cc8 = (t & 7) * 8;      // col (8-elem unit)
  const int cchunk = t & 7;

  f32x4_t xr[2][4][2];              // [buf][unit][half] — all indices compile-time
  f32x4_t acc[4][2] = {};

  auto loadX = [&](int buf, int k0) {
#pragma unroll
    for (int i = 0; i < 4; ++i) {
      const float* p = x + (size_t)(brow + crow + i * 32) * D_DIM + k0 + cc8;
      xr[buf][i][0] = *(const f32x4_t*)p;
      xr[buf][i][1] = *(const f32x4_t*)(p + 4);
    }
  };
  auto stageW = [&](int buf, int k0) {
#pragma unroll
    for (int i = 0; i < 2; ++i) {
      int row = i * 32 + (t >> 3);
      int sc = (cchunk ^ (row & 7)) * 8;      // pre-swizzled source (rule 21)
      gload16(Wrh + (size_t)row * D_DIM + k0 + sc, &Wh[buf][(i * 256 + t) * 8]);
      gload16(Wrl + (size_t)row * D_DIM + k0 + sc, &Wl[buf][(i * 256 + t) * 8]);
    }
  };

  stageW(0, kcb);
  loadX(0, kcb);

#pragma unroll
  for (int s = 0; s < 4; ++s) {
    const int k0 = kcb + s * 64;
    if (s < 3) { stageW((s + 1) & 1, k0 + 64); loadX((s + 1) & 1, k0 + 64); }
    // convert current x regs -> swizzled Ah/Al + fused Xb store
#pragma unroll
    for (int i = 0; i < 4; ++i) {
      int row = crow + i * 32;
      short8_t h, l;
      cvt_hilo8(xr[s & 1][i][0], xr[s & 1][i][1], h, l);
      int wch = (cchunk ^ (row & 7)) * 8;
      *(short8_t*)(Ah + row * 64 + wch) = h;
      *(short8_t*)(Al + row * 64 + wch) = l;
      *(short8_t*)(Xb + (size_t)(brow + row) * D_DIM + k0 + cc8) = h;
    }
    // newest-in-flight: 12 loads(s+1) + 4 Xb stores; everything older (incl. W(s)) retired
    if (s < 3) { WAIT_VM(16); } else { WAIT_VM(4); }
    BARR();
    short8_t ah[4][2], al[4][2], bh[2][2], bl[2][2];
#pragma unroll
    for (int m = 0; m < 4; ++m)
#pragma unroll
      for (int ks = 0; ks < 2; ++ks) {
        int row = wr * 64 + m * 16 + lr;
        int ch = ((kh + ks * 4) ^ (row & 7)) * 8;
        ah[m][ks] = *(const short8_t*)(Ah + row * 64 + ch);
        al[m][ks] = *(const short8_t*)(Al + row * 64 + ch);
      }
#pragma unroll
    for (int n = 0; n < 2; ++n)
#pragma unroll
      for (int ks = 0; ks < 2; ++ks) {
        int row = wc * 32 + n * 16 + lr;
        int ch = ((kh + ks * 4) ^ (row & 7)) * 8;
        bh[n][ks] = *(const short8_t*)(&Wh[s & 1][row * 64 + ch]);
        bl[n][ks] = *(const short8_t*)(&Wl[s & 1][row * 64 + ch]);
      }
#pragma unroll
    for (int m = 0; m < 4; ++m)
#pragma unroll
      for (int n = 0; n < 2; ++n)
#pragma unroll
        for (int ks = 0; ks < 2; ++ks) {
          acc[m][n] = __builtin_amdgcn_mfma_f32_16x16x32_bf16(ah[m][ks], bh[n][ks], acc[m][n], 0, 0, 0);
          acc[m][n] = __builtin_amdgcn_mfma_f32_16x16x32_bf16(al[m][ks], bh[n][ks], acc[m][n], 0, 0, 0);
          acc[m][n] = __builtin_amdgcn_mfma_f32_16x16x32_bf16(ah[m][ks], bl[n][ks], acc[m][n], 0, 0, 0);
        }
    BARR();
  }

  float* Pb = P + (size_t)blockIdx.y * N_TOK * K_EXP;
#pragma unroll
  for (int m = 0; m < 4; ++m)
#pragma unroll
    for (int n = 0; n < 2; ++n)
#pragma unroll
      for (int j = 0; j < 4; ++j) {
        int row = brow + wr * 64 + m * 16 + kh * 4 + j;
        int e = wc * 32 + n * 16 + lr;
        Pb[(size_t)row * K_EXP + e] = acc[m][n][j];
      }
}

// ---------------- per-token top-16 + softmax -> dense G (N,64) ----------------
__global__ void topk_kernel(const float* __restrict__ P, float* __restrict__ G) {
  int wid = threadIdx.x >> 6, lane = threadIdx.x & 63;
  int n = blockIdx.x * 4 + wid;
  float rem = 0.f;
#pragma unroll
  for (int c = 0; c < SPLIT_S; ++c)
    rem += P[((size_t)c * N_TOK + n) * K_EXP + lane];
  float topv[16]; int topi[16];
#pragma unroll
  for (int it = 0; it < 16; ++it) {
    float bv = rem; int bi = lane;
#pragma unroll
    for (int off = 32; off >= 1; off >>= 1) {
      float ov = __shfl_xor(bv, off);
      int oi = __shfl_xor(bi, off);
      if (ov > bv || (ov == bv && oi < bi)) { bv = ov; bi = oi; }
    }
    topv[it] = bv; topi[it] = bi;
    if (lane == bi) rem = -1e30f;
  }
  float mx = topv[0];
  float s = 0.f;
#pragma unroll
  for (int j = 0; j < 16; ++j) s += expf(topv[j] - mx);
  float g = 0.f;
#pragma unroll
  for (int j = 0; j < 16; ++j)
    if (topi[j] == lane) g = expf(topv[j] - mx) / s;
  G[(size_t)n * K_EXP + lane] = g;
}

// ---------------- 8-phase 256x256 MFMA GEMM (C = A(M,KD-slice) * B(N,KD-slice)^T) ----
// 512 thr = 8 waves (2M x 4N), BK=64, 16 K-tiles/block, 2 LDS buffers (128 KiB).
template <int KD, int EPI>   // EPI 0: bf16 partial out (stride KR); 1: f32*SCALE (stride D_DIM)
__global__ __launch_bounds__(512, 2)
void gemm8ph(const unsigned short* __restrict__ Aop,
             const unsigned short* __restrict__ Bop,
             void* __restrict__ Cout) {
  extern __shared__ unsigned short lds[];   // 2 x (A 256x64 + B 256x64) = 65536 shorts
  const int t = threadIdx.x;
  const int wid = t >> 6, lane = t & 63;
  const int wm = wid >> 2, wn = wid & 3;
  const int lr = lane & 15, kh = lane >> 4;

  int brow, bcol, kbeg;
  unsigned short* outb = nullptr;
  float* outf = nullptr;
  {
    int b = blockIdx.x;                    // 256 blocks, XCD-bijective remap
    int logical = (b & 7) * 32 + (b >> 3);
    if constexpr (EPI == 0) {
      int zb = logical >> 6;               // K split (4)
      int rem = logical & 63;
      brow = (rem >> 2) * 256;
      bcol = (rem & 3) * 256;
      kbeg = zb * KC_G;
      outb = (unsigned short*)Cout + (size_t)zb * N_TOK * KR;
    } else {
      brow = (logical >> 4) * 256;
      bcol = (logical & 15) * 256;
      kbeg = 0;
      outf = (float*)Cout;
    }
  }

  const int srow = t >> 3;                               // 0..63 within unit
  const int scoff = (((t & 7) ^ (srow & 7)) * 8);        // shorts
  const int ldoff = t * 8;                               // shorts
  const unsigned short* Abase = Aop + (size_t)(brow + srow) * KD + kbeg + scoff;
  const unsigned short* Bbase = Bop + (size_t)(bcol + srow) * KD + kbeg + scoff;

  auto stA = [&](int j, int T) {
    gload16(Abase + (size_t)j * 64 * KD + T * 64,
            lds + (T & 1) * 32768 + j * 4096 + ldoff);
  };
  auto stB = [&](int j, int T) {
    gload16(Bbase + (size_t)j * 64 * KD + T * 64,
            lds + (T & 1) * 32768 + 16384 + j * 4096 + ldoff);
  };
  auto rdA = [&](const unsigned short* LA, int m, int ks) -> short8_t {
    int r = wm * 128 + m * 16 + lr;
    int x = (ks * 32 + kh * 8) ^ ((lr & 7) << 3);
    return *(const short8_t*)(LA + r * 64 + x);
  };
  auto rdB = [&](const unsigned short* LB, int n, int ks) -> short8_t {
    int r = wn * 64 + n * 16 + lr;
    int x = (ks * 32 + kh * 8) ^ ((lr & 7) << 3);
    return *(const short8_t*)(LB + r * 64 + x);
  };

  f32x4_t acc[8][4] = {};
  short8_t bq[4][2], aq[2][2];

#define MFMA_QUAD(mb)                                                        \
  _Pragma("unroll")                                                          \
  for (int mm = 0; mm < 2; ++mm)                                             \
    _Pragma("unroll")                                                        \
    for (int n = 0; n < 4; ++n)                                              \
      _Pragma("unroll")                                                      \
      for (int ks = 0; ks < 2; ++ks)                                         \
        acc[(mb) + mm][n] = __builtin_amdgcn_mfma_f32_16x16x32_bf16(         \
            aq[mm][ks], bq[n][ks], acc[(mb) + mm][n], 0, 0, 0);

  stB(0, 0); stB(1, 0); stB(2, 0); stB(3, 0);
  stA(0, 0); stA(1, 0); stA(2, 0); stA(3, 0);
  stB(0, 1); stB(1, 1); stB(2, 1); stB(3, 1);
  stA(0, 1); stA(2, 1);
  WAIT_VM(6);
  BARR();

  for (int tt = 0; tt < 16; ++tt) {
    const unsigned short* LA = lds + (tt & 1) * 32768;
    const unsigned short* LB = LA + 16384;
#pragma unroll
    for (int n = 0; n < 4; ++n) { bq[n][0] = rdB(LB, n, 0); bq[n][1] = rdB(LB, n, 1); }
    aq[0][0] = rdA(LA, 0, 0); aq[0][1] = rdA(LA, 0, 1);
    aq[1][0] = rdA(LA, 1, 0); aq[1][1] = rdA(LA, 1, 1);
    if (tt + 1 < 16) { stA(1, tt + 1); stA(3, tt + 1); }
    BARR(); WAIT_LGKM0(); FENCE();
    __builtin_amdgcn_s_setprio(1);
    MFMA_QUAD(0)
    __builtin_amdgcn_s_setprio(0);
    BARR();
    aq[0][0] = rdA(LA, 2, 0); aq[0][1] = rdA(LA, 2, 1);
    aq[1][0] = rdA(LA, 3, 0); aq[1][1] = rdA(LA, 3, 1);
    if (tt + 2 < 16) { stB(0, tt + 2); stB(1, tt + 2); }
    WAIT_VM(10);
    BARR(); WAIT_LGKM0(); FENCE();
    __builtin_amdgcn_s_setprio(1);
    MFMA_QUAD(2)
    __builtin_amdgcn_s_setprio(0);
    BARR();
    aq[0][0] = rdA(LA, 4, 0); aq[0][1] = rdA(LA, 4, 1);
    aq[1][0] = rdA(LA, 5, 0); aq[1][1] = rdA(LA, 5, 1);
    if (tt + 2 < 16) { stB(2, tt + 2); stB(3, tt + 2); }
    BARR(); WAIT_LGKM0(); FENCE();
    __builtin_amdgcn_s_setprio(1);
    MFMA_QUAD(4)
    __builtin_amdgcn_s_setprio(0);
    BARR();
    aq[0][0] = rdA(LA, 6, 0); aq[0][1] = rdA(LA, 6, 1);
    aq[1][0] = rdA(LA, 7, 0); aq[1][1] = rdA(LA, 7, 1);
    if (tt + 2 < 16) { stA(0, tt + 2); stA(2, tt + 2); }
    WAIT_VM(8);
    BARR(); WAIT_LGKM0(); FENCE();
    __builtin_amdgcn_s_setprio(1);
    MFMA_QUAD(6)
    __builtin_amdgcn_s_setprio(0);
    BARR();
  }
#undef MFMA_QUAD

#pragma unroll
  for (int m = 0; m < 8; ++m) {
    int gr0 = brow + wm * 128 + m * 16 + kh * 4;
#pragma unroll
    for (int n = 0; n < 4; ++n) {
      int gc = bcol + wn * 64 + n * 16 + lr;
#pragma unroll
      for (int j = 0; j < 4; ++j) {
        if constexpr (EPI == 0)
          outb[(size_t)(gr0 + j) * KR + gc] = f2bf(acc[m][n][j]);
        else
          outf[(size_t)(gr0 + j) * D_DIM + gc] = acc[m][n][j] * SCALE_F;
      }
    }
  }
}

// ---------------- reduce split-K bf16 partials, apply gate, pack bf16 ----------------
__global__ void reduce_gate_pack(const unsigned short* __restrict__ Pgb,
                                 const float* __restrict__ G,
                                 unsigned short* __restrict__ Hgb) {
  int idx4 = blockIdx.x * blockDim.x + threadIdx.x;
  size_t i = (size_t)idx4 * 4;
  int n = (int)(i >> 10);
  int kr = (int)(i & 1023);
  float g = G[(size_t)n * K_EXP + (kr >> 4)];
  float s[4] = {0.f, 0.f, 0.f, 0.f};
#pragma unroll
  for (int z = 0; z < SPLIT_G; ++z) {
    u16x4_t v = *(const u16x4_t*)(Pgb + (size_t)z * N_TOK * KR + i);
#pragma unroll
    for (int j = 0; j < 4; ++j) s[j] += bf2f(v[j]);
  }
  u16x4_t o;
#pragma unroll
  for (int j = 0; j < 4; ++j) o[j] = f2bf(s[j] * g);
  *(u16x4_t*)(Hgb + i) = o;
}

// ---------------- launch ----------------
extern "C" void kernel_launch(void* const* d_in, const int* in_sizes, int n_in,
                              void* d_out, int out_size, void* d_ws, size_t ws_size,
                              hipStream_t stream) {
  const float* x  = (const float*)d_in[0];   // (2,2048,4096)
  const float* A  = (const float*)d_in[1];   // (64,16,4096)
  const float* B  = (const float*)d_in[2];   // (64,4096,16)
  const float* Wr = (const float*)d_in[3];   // (64,4096)
  float* out = (float*)d_out;

  char* ws = (char*)d_ws;
  size_t off = 0;
  auto alloc = [&](size_t bytes) { void* p = ws + off; off += (bytes + 255) & ~255ull; return p; };
  float*          P   = (float*)alloc((size_t)SPLIT_S * N_TOK * K_EXP * 4);   // 16 MB
  float*          G   = (float*)alloc((size_t)N_TOK * K_EXP * 4);             // 1 MB
  unsigned short* Xb  = (unsigned short*)alloc((size_t)N_TOK * D_DIM * 2);    // 32 MB
  unsigned short* Ab  = (unsigned short*)alloc((size_t)KR * D_DIM * 2);       // 8 MB
  unsigned short* Wb  = (unsigned short*)alloc((size_t)D_DIM * KR * 2);       // 8 MB
  unsigned short* Hgb = (unsigned short*)alloc((size_t)N_TOK * KR * 2);       // 8 MB
  unsigned short* Pgb = (unsigned short*)alloc((size_t)SPLIT_G * N_TOK * KR * 2); // 32 MB
  unsigned short* Wrh = (unsigned short*)alloc((size_t)K_EXP * D_DIM * 2);    // 0.5 MB
  unsigned short* Wrl = (unsigned short*)alloc((size_t)K_EXP * D_DIM * 2);    // 0.5 MB
  (void)ws_size; (void)in_sizes; (void)n_in; (void)out_size;

  (void)hipFuncSetAttribute((const void*)&gemm8ph<D_DIM, 0>,
                            hipFuncAttributeMaxDynamicSharedMemorySize, 131072);
  (void)hipFuncSetAttribute((const void*)&gemm8ph<KR, 1>,
                            hipFuncAttributeMaxDynamicSharedMemorySize, 131072);

  pack_f32_to_bf16<<<1024, 256, 0, stream>>>(A, Ab, KR * D_DIM / 4);
  pack_b_kernel<<<1024, 256, 0, stream>>>(B, Wb, K_EXP * D_DIM * 4);
  pack_wr<<<K_EXP * D_DIM / 4 / 256, 256, 0, stream>>>(Wr, Wrh, Wrl);

  scores_mfma<<<dim3(N_TOK / 128, SPLIT_S), 256, 0, stream>>>(x, Wrh, Wrl, P, Xb);
  topk_kernel<<<N_TOK / 4, 256, 0, stream>>>(P, G);

  // GEMM1: Pgb[z] = bf16(Xb @ Ab^T) over K-chunk z  (256 blocks: 16M x 4N x 4z)
  gemm8ph<D_DIM, 0><<<256, 512, 131072, stream>>>(Xb, Ab, Pgb);
  reduce_gate_pack<<<N_TOK * KR / 4 / 256, 256, 0, stream>>>(Pgb, G, Hgb);

  // GEMM2: out = SCALE * Hgb @ Wb^T  (256 blocks: 16M x 16N)
  gemm8ph<KR, 1><<<256, 512, 131072, stream>>>(Hgb, Wb, out);
}